// Round 1
// baseline (127.178 us; speedup 1.0000x reference)
//
#include <hip/hip_runtime.h>
#include <hip/hip_bf16.h>
#include <cstdint>

typedef unsigned short u16;
typedef __bf16 bf16x8 __attribute__((ext_vector_type(8)));
typedef float f32x4 __attribute__((ext_vector_type(4)));
typedef u16 u16x8 __attribute__((ext_vector_type(8)));

// Problem sizes (fixed by the reference): B=8, S=2048, I=256, H=256, M=1024
#define NX 4194304L   // x elems  (8*2048*256)
#define NW 65536L     // W elems  (256*256)
#define NM 2097152L   // mem elems (8*1024*256)
// ws layout (u16 elems): [x_bf 0..NX) [W_bf ..+NW) [mem_bf ..+NM) [key_bf ..+NX)
#define WS_W   (NX)
#define WS_MEM (NX + NW)
#define WS_KEY (NX + NW + NM)

__device__ __forceinline__ u16 f2bf_rne(float f) {
  union { float f; uint32_t u; } v; v.f = f;
  uint32_t r = v.u + 0x7fffu + ((v.u >> 16) & 1u);
  return (u16)(r >> 16);
}

// ---- Kernel 0: fp32 -> bf16 pre-convert of x, W, mem into ws ----
__global__ void convert_bf16_kernel(const float* __restrict__ x,
                                    const float* __restrict__ mem,
                                    const float* __restrict__ W,
                                    u16* __restrict__ ws) {
  long e = ((long)blockIdx.x * blockDim.x + threadIdx.x) * 8;
  if (e >= NX + NW + NM) return;
  const float* src; long l;
  if (e < NX)            { src = x;   l = e; }
  else if (e < NX + NW)  { src = W;   l = e - NX; }
  else                   { src = mem; l = e - NX - NW; }
  float4 f0 = *(const float4*)(src + l);
  float4 f1 = *(const float4*)(src + l + 4);
  u16x8 o;
  o[0]=f2bf_rne(f0.x); o[1]=f2bf_rne(f0.y); o[2]=f2bf_rne(f0.z); o[3]=f2bf_rne(f0.w);
  o[4]=f2bf_rne(f1.x); o[5]=f2bf_rne(f1.y); o[6]=f2bf_rne(f1.z); o[7]=f2bf_rne(f1.w);
  *(u16x8*)(ws + e) = o;
}

// ---- m97-style NT GEMM: C[M,N] = A[M,K] * B[N,K]^T, bf16 in / fp32 out ----
// 128x128 tile, BK=32, 256 threads (4 waves, 2x2 of 64x64), 16x16x32 bf16 MFMA.
#define BM 128
#define BN 128
#define BK 32

template<bool RELU, bool STORE_BF16>
__global__ __launch_bounds__(256, 2)
void gemm_nt(const u16* __restrict__ A, const u16* __restrict__ B,
             float* __restrict__ C, u16* __restrict__ Cbf,
             int M, int N, int K,
             long sA_batch, long sB_batch, long sC_batch)
{
  __shared__ __align__(16) u16 sA[BM * BK];   // 8 KB
  __shared__ __align__(16) u16 sB[BN * BK];   // 8 KB
  const int tid  = threadIdx.x;
  const int wave = tid >> 6;
  const int lane = tid & 63;
  const int quad = lane >> 4;      // 0..3
  const int r    = lane & 15;      // 0..15
  const int wm   = wave >> 1;      // wave row (0..1)
  const int wn   = wave & 1;       // wave col (0..1)
  const int bm   = blockIdx.y * BM;
  const int bn   = blockIdx.x * BN;
  const int batch = blockIdx.z;

  const char* Ab = (const char*)(A + (long)batch * sA_batch);
  const char* Bb = (const char*)(B + (long)batch * sB_batch);
  const long ldr = (long)K * 2;    // row stride in bytes (both A and B are [*,K])

  f32x4 acc[4][4];
  #pragma unroll
  for (int i = 0; i < 4; i++)
    #pragma unroll
    for (int j = 0; j < 4; j++)
      acc[i][j] = f32x4{0.f, 0.f, 0.f, 0.f};

  // staging: each thread issues 2x16B per tile; LDS dest is wave-uniform base,
  // HW adds lane*16 (global_load_lds constraint).
  const int o0 = wave * 1024 + lane * 16;  // this lane's logical byte offset

  for (int kt = 0; kt < K; kt += BK) {
    __syncthreads();   // previous iteration's reads done before overwrite
    #pragma unroll
    for (int rr = 0; rr < 2; rr++) {
      const int o    = rr * 4096 + o0;
      const int row  = o >> 6;     // 64 B per LDS row (BK*2)
      const int colb = o & 63;
      const char* ga = Ab + (long)(bm + row) * ldr + (long)kt * 2 + colb;
      const char* gb = Bb + (long)(bn + row) * ldr + (long)kt * 2 + colb;
      char* la = (char*)sA + rr * 4096 + wave * 1024;
      char* lb = (char*)sB + rr * 4096 + wave * 1024;
      __builtin_amdgcn_global_load_lds((const __attribute__((address_space(1))) void*)ga,
                                       (__attribute__((address_space(3))) void*)la, 16, 0, 0);
      __builtin_amdgcn_global_load_lds((const __attribute__((address_space(1))) void*)gb,
                                       (__attribute__((address_space(3))) void*)lb, 16, 0, 0);
    }
    __syncthreads();   // compiler emits vmcnt(0) drain before s_barrier

    // A-frag: A[m=lane&15][k=quad*8+j]; B-frag: B^T[n=lane&15][k=quad*8+j]
    bf16x8 af[4], bf[4];
    #pragma unroll
    for (int i = 0; i < 4; i++)
      af[i] = *(const bf16x8*)(sA + (wm * 64 + i * 16 + r) * BK + quad * 8);
    #pragma unroll
    for (int j = 0; j < 4; j++)
      bf[j] = *(const bf16x8*)(sB + (wn * 64 + j * 16 + r) * BK + quad * 8);
    #pragma unroll
    for (int i = 0; i < 4; i++)
      #pragma unroll
      for (int j = 0; j < 4; j++)
        acc[i][j] = __builtin_amdgcn_mfma_f32_16x16x32_bf16(af[i], bf[j], acc[i][j], 0, 0, 0);
  }

  // epilogue: C/D layout col=lane&15, row=quad*4+reg (verified m89/m91)
  float* Co = C + (long)batch * sC_batch;
  u16*   Bo = STORE_BF16 ? (Cbf + (long)batch * sC_batch) : nullptr;
  #pragma unroll
  for (int i = 0; i < 4; i++) {
    #pragma unroll
    for (int j = 0; j < 4; j++) {
      #pragma unroll
      for (int reg = 0; reg < 4; reg++) {
        const int row = bm + wm * 64 + i * 16 + quad * 4 + reg;
        const int col = bn + wn * 64 + j * 16 + r;
        float v = acc[i][j][reg];
        if (RELU) v = v > 0.f ? v : 0.f;
        const long idx = (long)row * N + col;
        Co[idx] = v;
        if (STORE_BF16) Bo[idx] = f2bf_rne(v);
      }
    }
  }
}

extern "C" void kernel_launch(void* const* d_in, const int* in_sizes, int n_in,
                              void* d_out, int out_size, void* d_ws, size_t ws_size,
                              hipStream_t stream) {
  const float* x   = (const float*)d_in[0];  // (8,2048,256)
  const float* mem = (const float*)d_in[1];  // (8,1024,256)
  const float* W   = (const float*)d_in[2];  // (256,256)
  float* out   = (float*)d_out;
  float* key_f = out;            // (16384,256)
  float* val_f = out + NX;       // (8,2048,1024)
  u16* ws     = (u16*)d_ws;      // needs 21.1 MB
  u16* x_bf   = ws;
  u16* W_bf   = ws + WS_W;
  u16* mem_bf = ws + WS_MEM;
  u16* key_bf = ws + WS_KEY;

  // 0) convert inputs to bf16 (6,356,992 elems / 8 per thread = 3104 blocks)
  const long tot = NX + NW + NM;
  convert_bf16_kernel<<<(int)(tot / 8 / 256), 256, 0, stream>>>(x, mem, W, ws);

  // 1) key = relu(x @ W^T): M=16384, N=256, K=256; dual-store fp32 + bf16
  dim3 g1(256 / BN, 16384 / BM, 1);
  gemm_nt<true, true><<<g1, 256, 0, stream>>>(x_bf, W_bf, key_f, key_bf,
                                              16384, 256, 256, 0, 0, 0);

  // 2) val_b = key_b @ mem_b^T: per batch M=2048, N=1024, K=256
  dim3 g2(1024 / BN, 2048 / BM, 8);
  gemm_nt<false, false><<<g2, 256, 0, stream>>>(key_bf, mem_bf, val_f, nullptr,
                                                2048, 1024, 256,
                                                (long)2048 * 256, (long)1024 * 256,
                                                (long)2048 * 1024);
}